// Round 2
// 122.403 us; speedup vs baseline: 1.0052x; 1.0052x over previous
//
#include <hip/hip_runtime.h>

// Hapke BRDF — elementwise, N=1M.
// R6 = R5 with compile fix: __builtin_nontemporal_store requires a NATIVE
// vector type, not HIP_vector_type<float,2>. Use ext_vector_type(2) alias
// for all 8B loads/stores. Structure unchanged from R5:
//  * 2 points/thread -> two INDEPENDENT dependency chains (R4 is one long
//    rcp/exp/sqrt serial chain per point; latency, not BW/VALU throughput,
//    is the gap vs the ~15.5us traffic floor)
//  * dwordx2 loads (24B/point-pair bases are 8B-aligned), halves VMEM insts
//  * nontemporal dwordx2 stores (output streamed, never re-read)
//  * __launch_bounds__(256,4) caps VGPR at 128 (4-pt variant collapsed occ).
// Math is operation-for-operation identical to R4 — no accuracy delta.

#define PIF  3.14159265358979323846f
#define EPSF 1e-5f

typedef float v2f __attribute__((ext_vector_type(2)));

__device__ __forceinline__ float rcp(float x)  { return __builtin_amdgcn_rcpf(x); }
__device__ __forceinline__ float rsq(float x)  { return __builtin_amdgcn_rsqf(x); }
__device__ __forceinline__ float sqf(float x)  { return __builtin_amdgcn_sqrtf(x); }
__device__ __forceinline__ float nz(float y, float r) { return (y != y) ? r : y; }
__device__ __forceinline__ float clamp1(float x) { return fminf(fmaxf(x, -1.0f), 1.0f); }
// Abramowitz-Stegun 4.4.45: |err| <= 6.7e-5 rad. phi only feeds phi/PI * E1
// inside a denominator >= ~0.9 — error impact ~2e-5, far under threshold slack.
__device__ __forceinline__ float acos_poly(float x) {
    float a = fabsf(x);
    float r = sqf(1.0f - a) *
              (1.5707288f + a * (-0.2121144f + a * (0.0742610f + a * (-0.0187293f))));
    return (x >= 0.0f) ? r : (PIF - r);
}

__device__ __forceinline__ void hapke_point(
    float lx, float ly, float lz,
    float vx, float vy, float vz,
    float nx, float ny, float nzc,
    float th, float hh, float B0v,
    float w0, float w1, float w2,
    float b0, float b1, float b2,
    float c0, float c1, float c2,
    float outv[3])
{
    // ci, cv in [0,1] (l,v flipped into normal's hemisphere by setup)
    float ci  = clamp1(nx*lx + ny*ly + nzc*lz);
    float cvv = clamp1(nx*vx + ny*vy + nzc*vz);
    float cg  = clamp1(lx*vx + ly*vy + lz*vz);
    float si  = sqf(1.0f - ci*ci);           // sin(acos x) — exact
    float sv  = sqf(1.0f - cvv*cvv);
    float cphi = clamp1((cg - ci*cvv) * rcp(si*sv + 1e-8f));
    float phipi = acos_poly(cphi) * (1.0f / PIF);

    // ff = exp(-2 tan((phi+EPS)/2)); cphi==-1 -> inf -> NaN -> shad=0 (matches ref)
    float ffu = (1.0f - cphi) * rcp(1.0f + cphi);
    float ff  = (cphi <= -1.0f) ? __builtin_inff() : __expf(-2.0f * sqf(ffu));

    float s = __sinf(th + EPSF), cth = __cosf(th + EPSF);
    float tt     = s * rcp(cth);             // tan(th+EPS); reused for tan(th), diff <= 2e-5
    float cot_th = cth * rcp(s);
    float cot_i  = ci * rcp(si);             // si=0 -> inf -> E*=0 (ref limit)
    float cot_e  = cvv * rcp(sv);

    float E1i = nz(__expf(-(2.0f/PIF) * cot_th * cot_i), 0.0f);
    float E1e = nz(__expf(-(2.0f/PIF) * cot_th * cot_e), 0.0f);
    float ct2 = cot_th * cot_th;
    float E2i = nz(__expf(-(1.0f/PIF) * ct2 * cot_i*cot_i), 0.0f);
    float E2e = nz(__expf(-(1.0f/PIF) * ct2 * cot_e*cot_e), 0.0f);

    float chit = rsq(1.0f + PIF * tt * tt);
    float etai = nz(chit * (ci  + si * tt * (E2i * rcp(2.0f - E1i))), 0.0f);
    float etae = nz(chit * (cvv + sv * tt * (E2e * rcp(2.0f - E1e))), 0.0f);

    float sp2 = 0.5f * (1.0f - cphi);        // sin^2(phi/2) — exact half-angle
    bool  ile = (ci >= cvv);                 // sza <= vza
    float Ea  = ile ? E1e : E1i;             // shared denominator: select, then ONE rcp
    float Eb  = ile ? E1i : E1e;
    float rd  = rcp(2.0f - Ea - phipi * Eb);
    float ymu  = (ile ? (E2e - sp2*E2i)      : (cphi*E2i + sp2*E2e)) * rd;
    float ymu0 = (ile ? (cphi*E2e + sp2*E2i) : (E2i - sp2*E2e)) * rd;
    float cv_e = nz(chit * (cvv + sv * tt * ymu ), cvv);  // _mu_eff
    float ci_e = nz(chit * (ci  + si * tt * ymu0), ci);   // _mu0_eff

    // _S (shadowing)
    float r_etai = rcp(etai), r_etae = rcp(etae);
    float ci_etai = ci * r_etai, cv_etae = cvv * r_etae;
    float temp = cv_e * r_etae * ci_etai * chit;
    float den  = 1.0f - ff + ff * chit * (ile ? ci_etai : cv_etae);
    float shad = nz(temp * rcp(den), 0.0f);  // ff=inf -> den=NaN -> 0 (matches ref)

    // B0/(1 + tan(g/2)/h) + 1 = B0*h/(h + tg2) + 1; tan(g/2)=sqrt((1-cg)/(1+cg))
    float tg2 = sqf((1.0f - cg) * rcp(1.0f + cg));
    float B   = B0v * hh * rcp(hh + tg2) + 1.0f;
    float tmp1 = ci_e * rcp((ci_e + cv_e) * ci);

    float logi = 0.5f * __logf(fabsf((1.0f + ci_e) * rcp(ci_e)));
    float loge = 0.5f * __logf(fabsf((1.0f + cv_e) * rcp(cv_e)));

    const float wk3[3] = {w0, w1, w2};
    const float bk3[3] = {b0, b1, b2};
    const float ck3[3] = {c0, c1, c2};
    #pragma unroll
    for (int k = 0; k < 3; ++k) {
        float wk = wk3[k], bk = bk3[k], ck = ck3[k];
        float b2 = bk * bk, bx = bk * cg;
        float t1 = 1.0f - 2.0f*bx + b2;      // >= (1-0.8)^2 = 0.04 > 0
        float t2 = 1.0f + 2.0f*bx + b2;
        float q1 = t1 * sqf(t1) + 1e-6f;
        float q2 = t2 * sqf(t2) + 1e-6f;
        float P  = (1.0f - b2) * (ck*q2 + (1.0f - ck)*q1) * rcp(q1*q2);
        float gamma = sqf(1.0f - wk);
        float ro = (1.0f - gamma) * rcp(1.0f + gamma);
        float Hi = nz(rcp(1.0f - wk*ci_e*(ro + (1.0f - 2.0f*ro*ci_e)*logi)), 1.0f);
        float Hv = nz(rcp(1.0f - wk*cv_e*(ro + (1.0f - 2.0f*ro*cv_e)*loge)), 1.0f);
        float tmp2 = P * B + Hi * Hv - 1.0f;
        outv[k] = wk * 0.25f * tmp1 * tmp2 * shad;   // w / HPK_SCL
    }
}

__global__ __launch_bounds__(256, 4)
void hapke_kernel(const float* __restrict__ pts2l, const float* __restrict__ pts2c,
                  const float* __restrict__ normal, const float* __restrict__ w,
                  const float* __restrict__ b, const float* __restrict__ c,
                  const float* __restrict__ theta, const float* __restrict__ h,
                  const float* __restrict__ B0, float* __restrict__ out, int N)
{
    int t  = blockIdx.x * blockDim.x + threadIdx.x;
    int p0 = t * 2;
    if (p0 >= N) return;

    if (p0 + 1 < N) {
        // Paired path: 6 floats per 3-vec array per thread, 8B-aligned -> dwordx2.
        const v2f* L2 = (const v2f*)pts2l;
        const v2f* V2 = (const v2f*)pts2c;
        const v2f* N2 = (const v2f*)normal;
        const v2f* W2 = (const v2f*)w;
        const v2f* Bb2 = (const v2f*)b;
        const v2f* C2 = (const v2f*)c;
        const v2f* T2 = (const v2f*)theta;
        const v2f* H2 = (const v2f*)h;
        const v2f* Z2 = (const v2f*)B0;

        int t3 = 3 * t;
        v2f la = L2[t3], lb = L2[t3+1], lc = L2[t3+2];
        v2f va = V2[t3], vb = V2[t3+1], vc = V2[t3+2];
        v2f na = N2[t3], nb = N2[t3+1], nc = N2[t3+2];
        v2f wa = W2[t3], wb = W2[t3+1], wc = W2[t3+2];
        v2f ba = Bb2[t3], bb = Bb2[t3+1], bc = Bb2[t3+2];
        v2f ca = C2[t3], cb = C2[t3+1], cc = C2[t3+2];
        v2f th2 = T2[t], h2 = H2[t], z2 = Z2[t];

        float oA[3], oB[3];
        // Point 0: (a.x, a.y, b.x) of each triplet-pair
        hapke_point(la.x, la.y, lb.x,  va.x, va.y, vb.x,  na.x, na.y, nb.x,
                    th2.x, h2.x, z2.x,
                    wa.x, wa.y, wb.x,  ba.x, ba.y, bb.x,  ca.x, ca.y, cb.x, oA);
        // Point 1: (b.y, c.x, c.y)
        hapke_point(lb.y, lc.x, lc.y,  vb.y, vc.x, vc.y,  nb.y, nc.x, nc.y,
                    th2.y, h2.y, z2.y,
                    wb.y, wc.x, wc.y,  bb.y, bc.x, bc.y,  cb.y, cc.x, cc.y, oB);

        v2f* O2 = (v2f*)out;
        v2f s0; s0.x = oA[0]; s0.y = oA[1];
        v2f s1; s1.x = oA[2]; s1.y = oB[0];
        v2f s2; s2.x = oB[1]; s2.y = oB[2];
        __builtin_nontemporal_store(s0, &O2[t3]);
        __builtin_nontemporal_store(s1, &O2[t3+1]);
        __builtin_nontemporal_store(s2, &O2[t3+2]);
    } else {
        // Odd tail (not taken at N=1048576, kept for generality)
        int i3 = p0 * 3;
        float oA[3];
        hapke_point(pts2l[i3], pts2l[i3+1], pts2l[i3+2],
                    pts2c[i3], pts2c[i3+1], pts2c[i3+2],
                    normal[i3], normal[i3+1], normal[i3+2],
                    theta[p0], h[p0], B0[p0],
                    w[i3], w[i3+1], w[i3+2],
                    b[i3], b[i3+1], b[i3+2],
                    c[i3], c[i3+1], c[i3+2], oA);
        out[i3] = oA[0]; out[i3+1] = oA[1]; out[i3+2] = oA[2];
    }
}

extern "C" void kernel_launch(void* const* d_in, const int* in_sizes, int n_in,
                              void* d_out, int out_size, void* d_ws, size_t ws_size,
                              hipStream_t stream) {
    const float* pts2l  = (const float*)d_in[0];
    const float* pts2c  = (const float*)d_in[1];
    const float* normal = (const float*)d_in[2];
    const float* w      = (const float*)d_in[3];
    const float* b      = (const float*)d_in[4];
    const float* c      = (const float*)d_in[5];
    const float* theta  = (const float*)d_in[6];
    const float* h      = (const float*)d_in[7];
    const float* B0     = (const float*)d_in[8];
    float* out = (float*)d_out;

    int N = in_sizes[6];
    const int block = 256;
    int nthreads = (N + 1) / 2;               // 2 points per thread
    int grid = (nthreads + block - 1) / block;
    hapke_kernel<<<grid, block, 0, stream>>>(pts2l, pts2c, normal, w, b, c,
                                             theta, h, B0, out, N);
}